// Round 11
// baseline (223.746 us; speedup 1.0000x reference)
//
#include <hip/hip_runtime.h>

// B=64,T=128,D=U=1024. M=8192 independent rows.
//   h' = reset?0:state
//   z = sig(x@wi_z + h'@wh_z + bz); r = sig(x@wi_r + h'@wh_r + br)
//   a = tanh(x@wi_a + (r*h')@wh_a + ba)   // (r*h') @ w  — * binds left of @
//   h_new = (1-z)h' + z*a; out = [h_new, h_new]
// Round 10: r9 schedule (counted vmcnt, stage-into-live-buffer, 2 bars/tile)
// on BIG tiles at 1 blk/CU with 8 drifting waves:
//   zr:   256x256, BK=64, 2x64KB LDS, per-wave 128x64 (acc 8x4), vmcnt(8)
//   cand: 256x128, BK=64, 2x48KB LDS, per-wave 64x64  (acc 4x4), vmcnt(6)
// Grids exactly 256 blocks = 1/CU; per-XCD M-chunks (A 4MB L2-resident).

typedef __attribute__((ext_vector_type(8))) short short8;
typedef __attribute__((ext_vector_type(4))) short short4v;
typedef __attribute__((ext_vector_type(4))) float floatx4;
typedef __attribute__((ext_vector_type(4))) float f32x4;

#define MROWS 8192
#define KTOT 2048
#define NU 1024
#define NKT 32            // K-tiles of 64
#define ZBUF 65536        // zr: A 32KB + B 32KB
#define CBUF 49152        // cand: A 32KB + B 16KB

__device__ __forceinline__ short f2bf(float f) {
  unsigned u = __builtin_bit_cast(unsigned, f);
  u += 0x7fffu + ((u >> 16) & 1u);  // RNE
  return (short)(u >> 16);
}
__device__ __forceinline__ float bf2f(short s) {
  unsigned u = ((unsigned)(unsigned short)s) << 16;
  return __builtin_bit_cast(float, u);
}
__device__ __forceinline__ float sigmoid_f(float v) { return 1.f / (1.f + __expf(-v)); }
__device__ __forceinline__ float tanh_f(float v) {
  float c = fminf(fmaxf(v, -15.f), 15.f);
  float e = __expf(2.f * c);
  return (e - 1.f) / (e + 1.f);
}

typedef __attribute__((address_space(3))) void* lds_vp;
typedef const __attribute__((address_space(1))) void* gbl_vp;
__device__ __forceinline__ void gload16(const void* g, void* lds) {
  __builtin_amdgcn_global_load_lds((gbl_vp)g, (lds_vp)lds, 16, 0, 0);
}

#define MF(a, b, c) __builtin_amdgcn_mfma_f32_16x16x32_bf16(a, b, c, 0, 0, 0)
#define VMCNT(n) asm volatile("s_waitcnt vmcnt(" #n ")" ::: "memory")
#define LGKM0() asm volatile("s_waitcnt lgkmcnt(0)" ::: "memory")
#define TILE_BAR()                  \
  do {                              \
    __builtin_amdgcn_s_barrier();   \
    asm volatile("" ::: "memory");  \
  } while (0)

// ---- prep 1: Wc[n][k] = (k<1024 ? w_i[k][n] : w_h[k-1024][n]) bf16 ----
__global__ __launch_bounds__(256) void wt_kernel(const float* __restrict__ w_i,
                                                 const float* __restrict__ w_h,
                                                 short* __restrict__ Wc) {
  __shared__ float tile[32][33];
  const int kb = blockIdx.x * 32;
  const int nb = blockIdx.y * 32;
  const float* src = (kb < 1024) ? w_i : w_h;
  const int kbl = kb & 1023;
  const int tx = threadIdx.x & 31;
  const int ty = threadIdx.x >> 5;
#pragma unroll
  for (int r = 0; r < 32; r += 8)
    tile[ty + r][tx] = src[(size_t)(kbl + ty + r) * 3072 + nb + tx];
  __syncthreads();
#pragma unroll
  for (int r = 0; r < 32; r += 8)
    Wc[(size_t)(nb + ty + r) * KTOT + kb + tx] = f2bf(tile[tx][ty + r]);
}

// ---- prep 2: xh_cat[m] = [bf16(x[m]) | bf16(reset?0:state[m])] ----
__global__ __launch_bounds__(256) void xh_kernel(const float* __restrict__ x,
                                                 const int* __restrict__ reset,
                                                 const float* __restrict__ state,
                                                 short* __restrict__ xhc) {
  const size_t i4 = (size_t)blockIdx.x * blockDim.x + threadIdx.x;
  const size_t e = i4 * 4;
  const int row = (int)(e >> 10);
  const int d = (int)(e & 1023);
  const float hm = reset[row] ? 0.f : 1.f;
  floatx4 fx = *(const floatx4*)(x + e);
  floatx4 fh = *(const floatx4*)(state + e);
  short4v cx, ch;
#pragma unroll
  for (int k = 0; k < 4; ++k) { cx[k] = f2bf(fx[k]); ch[k] = f2bf(fh[k] * hm); }
  *(short4v*)(xhc + (size_t)row * KTOT + d) = cx;
  *(short4v*)(xhc + (size_t)row * KTOT + 1024 + d) = ch;
}

// ================= zr: 256x256, 8 waves (2Mx4N), per-wave 128x64 =============
__global__ __launch_bounds__(512, 1) void zr_kernel(
    const short* __restrict__ xhc, const short* __restrict__ Wc,
    const float* __restrict__ bias, float* __restrict__ zbuf,
    short* __restrict__ rh) {
  extern __shared__ char lds[];
  const int tid = threadIdx.x;
  const int wave = tid >> 6, lane = tid & 63;
  const int wm = wave >> 2, wn = wave & 3;   // 2M x 4N
  const int lrow = lane & 15;
  const int g16 = (lane >> 4) << 4;
  const int swz = (lrow & 7) << 4;           // verified: 0 bank conflicts
  const int srow = lane >> 3;
  const int scol = ((lane & 7) ^ srow) * 8;  // pre-swizzled global k-col

  const int xcd = blockIdx.x & 7, bi = blockIdx.x >> 3;  // 256 blocks
  const int mtile = xcd * 4 + (bi & 3);      // 0..31 ; A-chunk 4MB per XCD
  const int ntile = bi >> 2;                 // 0..7
  const int m0 = mtile * 256, n0g = ntile * 256;

  const short* aS = xhc + (size_t)(m0 + wave * 32 + srow) * KTOT + scol;
  const short* bS = Wc + (size_t)(n0g + wave * 32 + srow) * KTOT + scol;
  const int dA = wave * 4096;
  const int dB = 32768 + wave * 4096;

  f32x4 acc[8][4];
#pragma unroll
  for (int i = 0; i < 8; ++i)
#pragma unroll
    for (int j = 0; j < 4; ++j) acc[i][j] = (f32x4){0.f, 0.f, 0.f, 0.f};

#define ZR_STAGE(t, bufp)                                                  \
  _Pragma("unroll") for (int g = 0; g < 4; ++g) {                          \
    gload16(aS + (size_t)g * 8 * KTOT + (t) * 64, (bufp) + dA + g * 1024); \
    gload16(bS + (size_t)g * 8 * KTOT + (t) * 64, (bufp) + dB + g * 1024); \
  }

  ZR_STAGE(0, lds);
  ZR_STAGE(1, lds + ZBUF);
  VMCNT(8);   // tile0's 8 landed; tile1's in flight
  TILE_BAR();

#pragma unroll 2
  for (int t = 0; t < NKT; ++t) {
    char* buf = lds + (t & 1) * ZBUF;
    short8 af[8], bq[4];
    // ---- ks0: read + MFMA ----
    {
      const int colb = g16 ^ swz;
      const char* pA = buf + (wm * 128 + lrow) * 128 + colb;
      const char* pB = buf + 32768 + (wn * 64 + lrow) * 128 + colb;
#pragma unroll
      for (int i = 0; i < 8; ++i) af[i] = *(const short8*)(pA + i * 2048);
#pragma unroll
      for (int j = 0; j < 4; ++j) bq[j] = *(const short8*)(pB + j * 2048);
    }
    LGKM0();
    __builtin_amdgcn_s_setprio(1);
#pragma unroll
    for (int i = 0; i < 8; ++i)
#pragma unroll
      for (int j = 0; j < 4; ++j) acc[i][j] = MF(af[i], bq[j], acc[i][j]);
    __builtin_amdgcn_s_setprio(0);
    // ---- ks1: read, then barrier, stage, MFMA ----
    {
      const int colb = (64 + g16) ^ swz;
      const char* pA = buf + (wm * 128 + lrow) * 128 + colb;
      const char* pB = buf + 32768 + (wn * 64 + lrow) * 128 + colb;
#pragma unroll
      for (int i = 0; i < 8; ++i) af[i] = *(const short8*)(pA + i * 2048);
#pragma unroll
      for (int j = 0; j < 4; ++j) bq[j] = *(const short8*)(pB + j * 2048);
    }
    LGKM0();       // all this wave's reads of buf complete
    TILE_BAR();    // block-wide: safe to overwrite buf
    if (t + 2 < NKT) { ZR_STAGE(t + 2, buf); }  // same-parity buffer
    __builtin_amdgcn_s_setprio(1);
#pragma unroll
    for (int i = 0; i < 8; ++i)
#pragma unroll
      for (int j = 0; j < 4; ++j) acc[i][j] = MF(af[i], bq[j], acc[i][j]);
    __builtin_amdgcn_s_setprio(0);
    if (t + 2 < NKT) { VMCNT(8); } else { VMCNT(0); }  // t+1 landed
    TILE_BAR();
  }
#undef ZR_STAGE

  const bool zh = (n0g < 1024);
#pragma unroll
  for (int j = 0; j < 4; ++j) {
    const int gcn = n0g + wn * 64 + j * 16 + lrow;
    const float bv = bias[gcn];
#pragma unroll
    for (int i = 0; i < 8; ++i) {
#pragma unroll
      for (int rg = 0; rg < 4; ++rg) {
        const int gr = m0 + wm * 128 + i * 16 + (lane >> 4) * 4 + rg;
        const float sv = sigmoid_f(acc[i][j][rg] + bv);
        if (zh) {
          zbuf[(size_t)gr * NU + gcn] = sv;
        } else {
          const int u = gcn - 1024;
          const float hv = bf2f(xhc[(size_t)gr * KTOT + 1024 + u]);
          rh[(size_t)gr * NU + u] = f2bf(sv * hv);
        }
      }
    }
  }
}

// ================= cand: 256x128, 8 waves (4Mx2N), per-wave 64x64 ============
__global__ __launch_bounds__(512, 1) void cand_kernel(
    const short* __restrict__ xhc, const short* __restrict__ rh,
    const short* __restrict__ Wc, const float* __restrict__ bias,
    const float* zbuf, float* out) {  // zbuf/out alias d_out: no restrict
  extern __shared__ char lds[];
  const int tid = threadIdx.x;
  const int wave = tid >> 6, lane = tid & 63;
  const int wm = wave >> 1, wn = wave & 1;   // 4M x 2N
  const int lrow = lane & 15;
  const int g16 = (lane >> 4) << 4;
  const int swz = (lrow & 7) << 4;
  const int srow = lane >> 3;
  const int scol = ((lane & 7) ^ srow) * 8;

  const int xcd = blockIdx.x & 7, bi = blockIdx.x >> 3;  // 256 blocks
  const int mtile = xcd * 4 + (bi & 3);      // 0..31 (256-row tiles)
  const int ntile = bi >> 2;                 // 0..7 (128-wide)
  const int m0 = mtile * 256, n0g = ntile * 128;

  const short* aX = xhc + (size_t)(m0 + wave * 32 + srow) * KTOT + scol;  // x cols
  const short* aR = rh + (size_t)(m0 + wave * 32 + srow) * NU + scol;
  const short* bS = Wc + (size_t)(2048 + n0g + wave * 16 + srow) * KTOT + scol;
  const int dA = wave * 4096;                 // A region 32KB (256 rows)
  const int dB = 32768 + wave * 2048;         // B region 16KB (128 rows)

  f32x4 acc[4][4];
#pragma unroll
  for (int i = 0; i < 4; ++i)
#pragma unroll
    for (int j = 0; j < 4; ++j) acc[i][j] = (f32x4){0.f, 0.f, 0.f, 0.f};

  // A: tiles 0..15 from x-half (stride KTOT), 16..31 from rh (stride NU)
#define CD_STAGE(t, bufp)                                                        \
  _Pragma("unroll") for (int g = 0; g < 4; ++g) {                                \
    if ((t) < 16)                                                                \
      gload16(aX + (size_t)g * 8 * KTOT + (t) * 64, (bufp) + dA + g * 1024);     \
    else                                                                         \
      gload16(aR + (size_t)g * 8 * NU + ((t) - 16) * 64, (bufp) + dA + g * 1024);\
  }                                                                              \
  _Pragma("unroll") for (int g = 0; g < 2; ++g)                                  \
    gload16(bS + (size_t)g * 8 * KTOT + (t) * 64, (bufp) + dB + g * 1024);

  CD_STAGE(0, lds);
  CD_STAGE(1, lds + CBUF);
  VMCNT(6);
  TILE_BAR();

#pragma unroll 2
  for (int t = 0; t < NKT; ++t) {
    char* buf = lds + (t & 1) * CBUF;
    short8 af[4], bq[4];
    // ---- ks0 ----
    {
      const int colb = g16 ^ swz;
      const char* pA = buf + (wm * 64 + lrow) * 128 + colb;
      const char* pB = buf + 32768 + (wn * 64 + lrow) * 128 + colb;
#pragma unroll
      for (int i = 0; i < 4; ++i) af[i] = *(const short8*)(pA + i * 2048);
#pragma unroll
      for (int j = 0; j < 4; ++j) bq[j] = *(const short8*)(pB + j * 2048);
    }
    LGKM0();
    __builtin_amdgcn_s_setprio(1);
#pragma unroll
    for (int i = 0; i < 4; ++i)
#pragma unroll
      for (int j = 0; j < 4; ++j) acc[i][j] = MF(af[i], bq[j], acc[i][j]);
    __builtin_amdgcn_s_setprio(0);
    // ---- ks1 ----
    {
      const int colb = (64 + g16) ^ swz;
      const char* pA = buf + (wm * 64 + lrow) * 128 + colb;
      const char* pB = buf + 32768 + (wn * 64 + lrow) * 128 + colb;
#pragma unroll
      for (int i = 0; i < 4; ++i) af[i] = *(const short8*)(pA + i * 2048);
#pragma unroll
      for (int j = 0; j < 4; ++j) bq[j] = *(const short8*)(pB + j * 2048);
    }
    LGKM0();
    TILE_BAR();
    if (t + 2 < NKT) { CD_STAGE(t + 2, buf); }
    __builtin_amdgcn_s_setprio(1);
#pragma unroll
    for (int i = 0; i < 4; ++i)
#pragma unroll
      for (int j = 0; j < 4; ++j) acc[i][j] = MF(af[i], bq[j], acc[i][j]);
    __builtin_amdgcn_s_setprio(0);
    if (t + 2 < NKT) { VMCNT(6); } else { VMCNT(0); }
    TILE_BAR();
  }
#undef CD_STAGE

#pragma unroll
  for (int j = 0; j < 4; ++j) {
    const int gc = n0g + wn * 64 + j * 16 + lrow;
    const float ba = bias[2048 + gc];
#pragma unroll
    for (int i = 0; i < 4; ++i) {
#pragma unroll
      for (int rg = 0; rg < 4; ++rg) {
        const int gr = m0 + wm * 64 + i * 16 + (lane >> 4) * 4 + rg;
        const float av = tanh_f(acc[i][j][rg] + ba);
        const float zv = zbuf[(size_t)gr * NU + gc];
        const float hv = bf2f(xhc[(size_t)gr * KTOT + 1024 + gc]);
        const float hn = (1.f - zv) * hv + zv * av;
        out[(size_t)gr * NU + gc] = hn;
        out[(size_t)MROWS * NU + (size_t)gr * NU + gc] = hn;  // overwrites zbuf slot (read-first, same thread)
      }
    }
  }
}

extern "C" void kernel_launch(void* const* d_in, const int* in_sizes, int n_in,
                              void* d_out, int out_size, void* d_ws, size_t ws_size,
                              hipStream_t stream) {
  const float* x = (const float*)d_in[0];
  const int* reset = (const int*)d_in[1];
  const float* state = (const float*)d_in[2];
  const float* w_i = (const float*)d_in[3];
  const float* w_h = (const float*)d_in[4];
  const float* bias = (const float*)d_in[5];
  float* out = (float*)d_out;

  short* Wc = (short*)d_ws;                    // [3072][2048] bf16, 12.6MB
  short* xhc = Wc + (size_t)3072 * KTOT;       // [8192][2048] bf16, 33.5MB
  short* rh = xhc + (size_t)MROWS * KTOT;      // [8192][1024] bf16, 16.8MB
  float* zbuf = out + (size_t)MROWS * NU;      // z in d_out 2nd half

  hipFuncSetAttribute(reinterpret_cast<const void*>(zr_kernel),
                      hipFuncAttributeMaxDynamicSharedMemorySize, 2 * ZBUF);
  hipFuncSetAttribute(reinterpret_cast<const void*>(cand_kernel),
                      hipFuncAttributeMaxDynamicSharedMemorySize, 2 * CBUF);

  wt_kernel<<<dim3(KTOT / 32, 3072 / 32), 256, 0, stream>>>(w_i, w_h, Wc);
  xh_kernel<<<dim3(MROWS * 1024 / 4 / 256), 256, 0, stream>>>(x, reset, state, xhc);

  zr_kernel<<<dim3(256), 512, 2 * ZBUF, stream>>>(xhc, Wc, bias, zbuf, rh);
  cand_kernel<<<dim3(256), 512, 2 * CBUF, stream>>>(xhc, rh, Wc, bias, zbuf, out);
}

// Round 12
// 158.478 us; speedup vs baseline: 1.4118x; 1.4118x over previous
//
#include <hip/hip_runtime.h>

// B=64,T=128,D=U=1024. M=8192 independent rows.
//   h' = reset?0:state
//   z = sig(x@wi_z + h'@wh_z + bz); r = sig(x@wi_r + h'@wh_r + br)
//   a = tanh(x@wi_a + (r*h')@wh_a + ba)   // (r*h') @ w  — * binds left of @
//   h_new = (1-z)h' + z*a; out = [h_new, h_new]
// Round 11: revert to r9 (best: 162.3us; zr 90us) + merge the two prep
// kernels into one dispatch. r9 GEMM structure (verified):
//   128x128 tile, BK=64, 4 waves, 2-buf 64KB -> 2 blocks/CU (TLP covers
//   serialization) + counted vmcnt(8) (stage t+2 into live buffer).

typedef __attribute__((ext_vector_type(8))) short short8;
typedef __attribute__((ext_vector_type(4))) short short4v;
typedef __attribute__((ext_vector_type(4))) float floatx4;
typedef __attribute__((ext_vector_type(4))) float f32x4;

#define MROWS 8192
#define KTOT 2048
#define NU 1024
#define NKT 32            // K-tiles of 64
#define TBUF 32768        // A 16KB + B 16KB
#define TLDS (2 * TBUF)   // 64KB -> 2 blocks/CU

__device__ __forceinline__ short f2bf(float f) {
  unsigned u = __builtin_bit_cast(unsigned, f);
  u += 0x7fffu + ((u >> 16) & 1u);  // RNE
  return (short)(u >> 16);
}
__device__ __forceinline__ float bf2f(short s) {
  unsigned u = ((unsigned)(unsigned short)s) << 16;
  return __builtin_bit_cast(float, u);
}
__device__ __forceinline__ float sigmoid_f(float v) { return 1.f / (1.f + __expf(-v)); }
__device__ __forceinline__ float tanh_f(float v) {
  float c = fminf(fmaxf(v, -15.f), 15.f);
  float e = __expf(2.f * c);
  return (e - 1.f) / (e + 1.f);
}

typedef __attribute__((address_space(3))) void* lds_vp;
typedef const __attribute__((address_space(1))) void* gbl_vp;
__device__ __forceinline__ void gload16(const void* g, void* lds) {
  __builtin_amdgcn_global_load_lds((gbl_vp)g, (lds_vp)lds, 16, 0, 0);
}

#define MF(a, b, c) __builtin_amdgcn_mfma_f32_16x16x32_bf16(a, b, c, 0, 0, 0)
#define VMCNT(n) asm volatile("s_waitcnt vmcnt(" #n ")" ::: "memory")
#define LGKM0() asm volatile("s_waitcnt lgkmcnt(0)" ::: "memory")
#define TILE_BAR()                  \
  do {                              \
    __builtin_amdgcn_s_barrier();   \
    asm volatile("" ::: "memory");  \
  } while (0)

// ---- merged prep: blocks [0,6144): Wc transpose; [6144,14336): xh convert ---
//   Wc[n][k] = (k<1024 ? w_i[k][n] : w_h[k-1024][n]) bf16   (K-contiguous rows)
//   xh_cat[m] = [bf16(x[m]) | bf16(reset?0:state[m])]
__global__ __launch_bounds__(256) void prep_kernel(
    const float* __restrict__ w_i, const float* __restrict__ w_h,
    short* __restrict__ Wc, const float* __restrict__ x,
    const int* __restrict__ reset, const float* __restrict__ state,
    short* __restrict__ xhc) {
  __shared__ float tile[32][33];
  const int b = blockIdx.x;
  if (b < 6144) {
    // weight transpose+convert: kb in [0,2048), nb in [0,3072)
    const int kb = (b & 63) * 32;
    const int nb = (b >> 6) * 32;
    const float* src = (kb < 1024) ? w_i : w_h;
    const int kbl = kb & 1023;
    const int tx = threadIdx.x & 31;
    const int ty = threadIdx.x >> 5;
#pragma unroll
    for (int r = 0; r < 32; r += 8)
      tile[ty + r][tx] = src[(size_t)(kbl + ty + r) * 3072 + nb + tx];
    __syncthreads();
#pragma unroll
    for (int r = 0; r < 32; r += 8)
      Wc[(size_t)(nb + ty + r) * KTOT + kb + tx] = f2bf(tile[tx][ty + r]);
  } else {
    const size_t i4 = (size_t)(b - 6144) * 256 + threadIdx.x;
    const size_t e = i4 * 4;
    const int row = (int)(e >> 10);
    const int d = (int)(e & 1023);
    const float hm = reset[row] ? 0.f : 1.f;
    floatx4 fx = *(const floatx4*)(x + e);
    floatx4 fh = *(const floatx4*)(state + e);
    short4v cx, ch;
#pragma unroll
    for (int k = 0; k < 4; ++k) { cx[k] = f2bf(fx[k]); ch[k] = f2bf(fh[k] * hm); }
    *(short4v*)(xhc + (size_t)row * KTOT + d) = cx;
    *(short4v*)(xhc + (size_t)row * KTOT + 1024 + d) = ch;
  }
}

// ================= zr: 128x128 tile, 4 waves, per-wave 64x64 =================
__global__ __launch_bounds__(256, 2) void zr_kernel(
    const short* __restrict__ xhc, const short* __restrict__ Wc,
    const float* __restrict__ bias, float* __restrict__ zbuf,
    short* __restrict__ rh) {
  extern __shared__ char lds[];
  const int tid = threadIdx.x;
  const int wave = tid >> 6, lane = tid & 63;
  const int wm = wave >> 1, wn = wave & 1;   // 2M x 2N waves
  const int lrow = lane & 15;
  const int g16 = (lane >> 4) << 4;
  const int swz = (lrow & 7) << 4;           // read-side XOR (verified: 0 conflicts)
  const int srow = lane >> 3;                // staging row within 8-group
  const int scol = ((lane & 7) ^ srow) * 8;  // pre-swizzled global k-col (shorts)

  const int xcd = blockIdx.x & 7, bi = blockIdx.x >> 3;  // 1024 blocks
  const int mtile = xcd * 8 + (bi & 7);      // A-chunk 4MB L2-resident per XCD
  const int ntile = bi >> 3;                 // 0..15
  const int m0 = mtile * 128, n0g = ntile * 128;

  const short* aS = xhc + (size_t)(m0 + wave * 32 + srow) * KTOT + scol;
  const short* bS = Wc + (size_t)(n0g + wave * 32 + srow) * KTOT + scol;
  const int dA = wave * 4096;
  const int dB = 16384 + wave * 4096;

  f32x4 acc[4][4];
#pragma unroll
  for (int i = 0; i < 4; ++i)
#pragma unroll
    for (int j = 0; j < 4; ++j) acc[i][j] = (f32x4){0.f, 0.f, 0.f, 0.f};

#define ZR_STAGE(t, bufp)                                                  \
  _Pragma("unroll") for (int g = 0; g < 4; ++g) {                          \
    gload16(aS + (size_t)g * 8 * KTOT + (t) * 64, (bufp) + dA + g * 1024); \
    gload16(bS + (size_t)g * 8 * KTOT + (t) * 64, (bufp) + dB + g * 1024); \
  }

  ZR_STAGE(0, lds);
  ZR_STAGE(1, lds + TBUF);
  VMCNT(8);   // tile0's 8 landed; tile1's may fly
  TILE_BAR();

#pragma unroll 2
  for (int t = 0; t < NKT; ++t) {
    char* buf = lds + (t & 1) * TBUF;
    short8 af[2][4], bq[2][4];
#pragma unroll
    for (int ks = 0; ks < 2; ++ks) {
      const int colb = ((ks * 64 + g16) ^ swz);
      const char* pA = buf + (wm * 64 + lrow) * 128 + colb;
      const char* pB = buf + 16384 + (wn * 64 + lrow) * 128 + colb;
#pragma unroll
      for (int i = 0; i < 4; ++i) af[ks][i] = *(const short8*)(pA + i * 2048);
#pragma unroll
      for (int j = 0; j < 4; ++j) bq[ks][j] = *(const short8*)(pB + j * 2048);
    }
    LGKM0();       // wave's reads complete before any wave overwrites buf
    TILE_BAR();    // block-wide: safe to stage into this buffer
    if (t + 2 < NKT) { ZR_STAGE(t + 2, buf); }  // same parity buffer
    __builtin_amdgcn_s_setprio(1);
#pragma unroll
    for (int ks = 0; ks < 2; ++ks)
#pragma unroll
      for (int i = 0; i < 4; ++i)
#pragma unroll
        for (int j = 0; j < 4; ++j)
          acc[i][j] = MF(af[ks][i], bq[ks][j], acc[i][j]);
    __builtin_amdgcn_s_setprio(0);
    if (t + 2 < NKT) { VMCNT(8); } else { VMCNT(0); }  // t+1 landed
    TILE_BAR();
  }
#undef ZR_STAGE

  const bool zh = (n0g < 1024);
#pragma unroll
  for (int j = 0; j < 4; ++j) {
    const int gcn = n0g + wn * 64 + j * 16 + lrow;
    const float bv = bias[gcn];
#pragma unroll
    for (int i = 0; i < 4; ++i) {
#pragma unroll
      for (int rg = 0; rg < 4; ++rg) {
        const int gr = m0 + wm * 64 + i * 16 + (lane >> 4) * 4 + rg;
        const float sv = sigmoid_f(acc[i][j][rg] + bv);
        if (zh) {
          zbuf[(size_t)gr * NU + gcn] = sv;
        } else {
          const int u = gcn - 1024;
          const float hv = bf2f(xhc[(size_t)gr * KTOT + 1024 + u]);
          rh[(size_t)gr * NU + u] = f2bf(sv * hv);
        }
      }
    }
  }
}

// ================= cand: 128x128 tile, 4 waves, per-wave 64x64 =================
__global__ __launch_bounds__(256, 2) void cand_kernel(
    const short* __restrict__ xhc, const short* __restrict__ rh,
    const short* __restrict__ Wc, const float* __restrict__ bias,
    const float* zbuf, float* out) {  // zbuf/out alias d_out: no restrict
  extern __shared__ char lds[];
  const int tid = threadIdx.x;
  const int wave = tid >> 6, lane = tid & 63;
  const int wm = wave >> 1, wn = wave & 1;
  const int lrow = lane & 15;
  const int g16 = (lane >> 4) << 4;
  const int swz = (lrow & 7) << 4;
  const int srow = lane >> 3;
  const int scol = ((lane & 7) ^ srow) * 8;

  const int xcd = blockIdx.x & 7, bi = blockIdx.x >> 3;  // 512 blocks
  const int mtile = xcd * 8 + (bi & 7);
  const int ntile = bi >> 3;                 // 0..7
  const int m0 = mtile * 128, n0g = ntile * 128;

  const short* aX = xhc + (size_t)(m0 + wave * 32 + srow) * KTOT + scol;  // x cols
  const short* aR = rh + (size_t)(m0 + wave * 32 + srow) * NU + scol;
  const short* bS = Wc + (size_t)(2048 + n0g + wave * 32 + srow) * KTOT + scol;
  const int dA = wave * 4096;
  const int dB = 16384 + wave * 4096;

  f32x4 acc[4][4];
#pragma unroll
  for (int i = 0; i < 4; ++i)
#pragma unroll
    for (int j = 0; j < 4; ++j) acc[i][j] = (f32x4){0.f, 0.f, 0.f, 0.f};

  // A: tiles 0..15 from x-half (stride KTOT), 16..31 from rh (stride NU)
#define CD_STAGE(t, bufp)                                                        \
  _Pragma("unroll") for (int g = 0; g < 4; ++g) {                                \
    if ((t) < 16)                                                                \
      gload16(aX + (size_t)g * 8 * KTOT + (t) * 64, (bufp) + dA + g * 1024);     \
    else                                                                         \
      gload16(aR + (size_t)g * 8 * NU + ((t) - 16) * 64, (bufp) + dA + g * 1024);\
    gload16(bS + (size_t)g * 8 * KTOT + (t) * 64, (bufp) + dB + g * 1024);       \
  }

  CD_STAGE(0, lds);
  CD_STAGE(1, lds + TBUF);
  VMCNT(8);
  TILE_BAR();

#pragma unroll 2
  for (int t = 0; t < NKT; ++t) {
    char* buf = lds + (t & 1) * TBUF;
    short8 af[2][4], bq[2][4];
#pragma unroll
    for (int ks = 0; ks < 2; ++ks) {
      const int colb = ((ks * 64 + g16) ^ swz);
      const char* pA = buf + (wm * 64 + lrow) * 128 + colb;
      const char* pB = buf + 16384 + (wn * 64 + lrow) * 128 + colb;
#pragma unroll
      for (int i = 0; i < 4; ++i) af[ks][i] = *(const short8*)(pA + i * 2048);
#pragma unroll
      for (int j = 0; j < 4; ++j) bq[ks][j] = *(const short8*)(pB + j * 2048);
    }
    LGKM0();
    TILE_BAR();
    if (t + 2 < NKT) { CD_STAGE(t + 2, buf); }
    __builtin_amdgcn_s_setprio(1);
#pragma unroll
    for (int ks = 0; ks < 2; ++ks)
#pragma unroll
      for (int i = 0; i < 4; ++i)
#pragma unroll
        for (int j = 0; j < 4; ++j)
          acc[i][j] = MF(af[ks][i], bq[ks][j], acc[i][j]);
    __builtin_amdgcn_s_setprio(0);
    if (t + 2 < NKT) { VMCNT(8); } else { VMCNT(0); }
    TILE_BAR();
  }
#undef CD_STAGE

#pragma unroll
  for (int j = 0; j < 4; ++j) {
    const int gc = n0g + wn * 64 + j * 16 + lrow;
    const float ba = bias[2048 + gc];
#pragma unroll
    for (int i = 0; i < 4; ++i) {
#pragma unroll
      for (int rg = 0; rg < 4; ++rg) {
        const int gr = m0 + wm * 64 + i * 16 + (lane >> 4) * 4 + rg;
        const float av = tanh_f(acc[i][j][rg] + ba);
        const float zv = zbuf[(size_t)gr * NU + gc];
        const float hv = bf2f(xhc[(size_t)gr * KTOT + 1024 + gc]);
        const float hn = (1.f - zv) * hv + zv * av;
        out[(size_t)gr * NU + gc] = hn;
        out[(size_t)MROWS * NU + (size_t)gr * NU + gc] = hn;  // overwrites zbuf slot (read-first, same thread)
      }
    }
  }
}

extern "C" void kernel_launch(void* const* d_in, const int* in_sizes, int n_in,
                              void* d_out, int out_size, void* d_ws, size_t ws_size,
                              hipStream_t stream) {
  const float* x = (const float*)d_in[0];
  const int* reset = (const int*)d_in[1];
  const float* state = (const float*)d_in[2];
  const float* w_i = (const float*)d_in[3];
  const float* w_h = (const float*)d_in[4];
  const float* bias = (const float*)d_in[5];
  float* out = (float*)d_out;

  short* Wc = (short*)d_ws;                    // [3072][2048] bf16, 12.6MB
  short* xhc = Wc + (size_t)3072 * KTOT;       // [8192][2048] bf16, 33.5MB
  short* rh = xhc + (size_t)MROWS * KTOT;      // [8192][1024] bf16, 16.8MB
  float* zbuf = out + (size_t)MROWS * NU;      // z in d_out 2nd half

  hipFuncSetAttribute(reinterpret_cast<const void*>(zr_kernel),
                      hipFuncAttributeMaxDynamicSharedMemorySize, TLDS);
  hipFuncSetAttribute(reinterpret_cast<const void*>(cand_kernel),
                      hipFuncAttributeMaxDynamicSharedMemorySize, TLDS);

  // merged prep: 6144 transpose blocks + 8192 convert blocks
  prep_kernel<<<dim3(14336), 256, 0, stream>>>(w_i, w_h, Wc, x, reset, state, xhc);

  zr_kernel<<<dim3(1024), 256, TLDS, stream>>>(xhc, Wc, bias, zbuf, rh);
  cand_kernel<<<dim3(512), 256, TLDS, stream>>>(xhc, rh, Wc, bias, zbuf, out);
}